// Round 6
// baseline (25410.172 us; speedup 1.0000x reference)
//
#include <hip/hip_runtime.h>
#include <stdint.h>
#include <stddef.h>

// ---------------------------------------------------------------------------
// Autoregressive decoder for MI355X (gfx950) — multi-launch correctness anchor.
// Inputs/outputs are FP32 (per reference); lens int32.
// 400 steps, each = 7 small kernels on one stream (graph-captured):
//   k_mel (reduce mel/gate partials) -> k_s1 (GRU0 + write outputs t-1)
//   -> k_s2 (GRU1) -> k_s2b (gh0'/gh1'/u~/c) -> k_s3 (attention partials)
//   -> k_red (reduce ctx partials) -> k_s4 (co GEMM, mel/gate partials).
// NO grid barriers, NO device atomics: kernel boundaries provide ordering.
// GEMVs via v_mfma_f32_16x16x32_bf16 (weights pre-rounded to bf16), fp32 acc.
// scores = u~ . enc[b,t] + (h1.b_attn); softmax w/o max-sub, clamped +-70.
// ---------------------------------------------------------------------------

#define TM  400

typedef unsigned short ushort_t;
typedef short  short8  __attribute__((ext_vector_type(8)));
typedef float  float4v __attribute__((ext_vector_type(4)));

#define DEVI static __device__ __forceinline__

// swizzled-weight segment bases (in shorts, within g_sw)
#define SB_IH0  0
#define SB_IH1  393216
#define SB_HH0  3538944
#define SB_HH1  6684672
#define SB_AT   9830400
#define SB_WC   10878976
#define SW_TOT  12976128

__device__ __align__(16) ushort_t g_sw[SW_TOT];
__device__ __align__(16) ushort_t g_h0b[32768], g_h1b[32768];
__device__ __align__(16) float g_h0f[32768], g_h1f[32768];
__device__ __align__(16) float g_ubuf[32768], g_ctxn[32768];
__device__ __align__(16) float g_gh0[98304], g_gh1[98304];
__device__ __align__(16) float g_cbuf[32], g_sden[32];
__device__ __align__(16) float g_melsum[4096], g_gatesum[32];
__device__ __align__(16) float g_pctx[262144];   // [8 slots][32 b][1024]
__device__ __align__(16) float g_pden[256];      // [8 slots][32 b]
__device__ __align__(16) float g_pmel[262144];   // [64 wg][32 b][128 m]
__device__ __align__(16) float g_pgate[2048];    // [64 wg][32 b]

DEVI ushort_t f2b(float f) {                // float -> bf16 bits, RNE
  union { float f; uint32_t u; } c; c.f = f;
  uint32_t u = c.u + 0x7fffu + ((c.u >> 16) & 1u);
  return (ushort_t)(u >> 16);
}
DEVI float sigm(float x) { return 1.f / (1.f + __expf(-x)); }

DEVI float4v mfma16(short8 a, short8 b, float4v c) {
  return __builtin_amdgcn_mfma_f32_16x16x32_bf16(a, b, c, 0, 0, 0);
}

DEVI short8 frag_bias(const float* p, const float* bias) {
  short8 r;
#pragma unroll
  for (int i = 0; i < 8; ++i) r[i] = (short)f2b(p[i] + bias[i]);
  return r;
}
DEVI short8 frag_scale(const float* p, float s) {
  short8 r;
#pragma unroll
  for (int i = 0; i < 8; ++i) r[i] = (short)f2b(p[i] * s);
  return r;
}

// A: bf16 [32 x K] row-major; B: pre-swizzled frags. One 16x16 output tile.
DEVI float4v gemm_bf16(const ushort_t* Ab, int K, const ushort_t* Bw,
                       int ntile, int mu, int lane) {
  float4v acc = {0.f, 0.f, 0.f, 0.f};
  const int KB = K >> 5;
  const ushort_t* a = Ab + (size_t)(mu * 16 + (lane & 15)) * K + ((lane >> 4) << 3);
  const ushort_t* b = Bw + ((size_t)ntile * KB * 64 + lane) * 8;
  for (int kb = 0; kb < KB; ++kb) {
    short8 av = *(const short8*)(a + kb * 32);
    short8 bv = *(const short8*)(b + (size_t)kb * 512);
    acc = mfma16(av, bv, acc);
  }
  return acc;
}

// S1 gemm: A = melsum(fp32) + bp(fp32) -> bf16, K = 128
DEVI float4v gemm_s1(const float* mp, const float* bp, const ushort_t* Bw,
                     int ntile, int mu, int lane) {
  float4v acc = {0.f, 0.f, 0.f, 0.f};
  const int m = mu * 16 + (lane & 15), ko = (lane >> 4) << 3;
  const ushort_t* b = Bw + ((size_t)ntile * 4 * 64 + lane) * 8;
  for (int kb = 0; kb < 4; ++kb) {
    short8 av = frag_bias(mp + m * 128 + kb * 32 + ko, bp + kb * 32 + ko);
    acc = mfma16(av, *(const short8*)(b + (size_t)kb * 512), acc);
  }
  return acc;
}

// S4 gemm: A = [h1 bf16 (k<1024) | ctx*inv (k>=1024)], K = 2048
DEVI float4v gemm_s4(const ushort_t* h1b, const float* ctxn, const float* sden,
                     const ushort_t* Bw, int ntile, int mu, int lane) {
  float4v acc = {0.f, 0.f, 0.f, 0.f};
  const int m = mu * 16 + (lane & 15), ko = (lane >> 4) << 3;
  const ushort_t* a0 = h1b + m * 1024 + ko;
  const float* a1 = ctxn + m * 1024 + ko;
  const float den = sden[m];
  const float inv = (den > 1e-35f) ? (1.f / den) : 0.f;
  const ushort_t* b = Bw + ((size_t)ntile * 64 * 64 + lane) * 8;
  for (int kb = 0; kb < 32; ++kb)
    acc = mfma16(*(const short8*)(a0 + kb * 32), *(const short8*)(b + (size_t)kb * 512), acc);
  for (int kb = 32; kb < 64; ++kb) {
    short8 av = frag_scale(a1 + (kb - 32) * 32, inv);
    acc = mfma16(av, *(const short8*)(b + (size_t)kb * 512), acc);
  }
  return acc;
}

// scatter C-fragment into LDS: sh[q*256 + m*16 + n]
DEVI void put_tile(float* sh, int q, int lane, float4v a) {
  const int base = q * 256 + (lane & 15);
#pragma unroll
  for (int i = 0; i < 4; ++i) sh[base + ((lane >> 4) * 4 + i) * 16] = a[i];
}

// ---------------------------------------------------------------------------
// Prologue: round fp32 weights to bf16 and repack into B-fragment order.
// lane L holds B[k = kb*32 + (L>>4)*8 + i][n = ntile*16 + (L&15)]
// ---------------------------------------------------------------------------
__global__ void k_swz(const float* __restrict__ W0, const float* __restrict__ W1,
                      const float* __restrict__ W2, const float* __restrict__ W3,
                      const float* __restrict__ WA, const float* __restrict__ WC) {
  long fid = (long)blockIdx.x * 256 + threadIdx.x;
  if (fid >= 1622016) return;
  const float* src; int N, K; long base, local; bool tr = false;
  if      (fid < 49152)   { src = W0; N = 3072; K = 128;  base = SB_IH0; local = fid; }
  else if (fid < 442368)  { src = W1; N = 3072; K = 1024; base = SB_IH1; local = fid - 49152; }
  else if (fid < 835584)  { src = W2; N = 3072; K = 1024; base = SB_HH0; local = fid - 442368; }
  else if (fid < 1228800) { src = W3; N = 3072; K = 1024; base = SB_HH1; local = fid - 835584; }
  else if (fid < 1359872) { src = WA; N = 1024; K = 1024; base = SB_AT;  local = fid - 1228800; tr = true; }
  else                    { src = WC; N = 1024; K = 2048; base = SB_WC;  local = fid - 1359872; }
  const int L = (int)(local & 63);
  long rest = local >> 6;
  const int KB = K >> 5;
  const int kb = (int)(rest % KB);
  const int nt = (int)(rest / KB);
  const int n  = nt * 16 + (L & 15);
  const int k0 = kb * 32 + ((L >> 4) << 3);
  short8 r;
#pragma unroll
  for (int i = 0; i < 8; ++i) {
    float f = tr ? src[(size_t)(k0 + i) * N + n] : src[(size_t)n * K + (k0 + i)];
    r[i] = (short)f2b(f);
  }
  *(short8*)(g_sw + base + local * 8) = r;
}

// Prologue: init states + mask output (fp32).
__global__ void k_init(const float* __restrict__ ehid, const int* __restrict__ lens,
                       float* __restrict__ out, int out_size) {
  int i = blockIdx.x * 256 + threadIdx.x;
  if (i < 32768) { float v = ehid[i]; g_h0f[i] = v; g_h0b[i] = f2b(v); }
  else if (i < 65536) { int j = i - 32768; float v = ehid[32768 + j]; g_h1f[j] = v; g_h1b[j] = f2b(v); }
  else if (i < 78336) {
    int mi = i - 65536; int b = mi / 400, tt = mi % 400;
    int idx = 1651200 + mi;
    if (idx < out_size)
      out[idx] = (tt > lens[b]) ? 1.0f : 0.0f;
  }
}

// Reduce mel/gate partials (from k_s4 of the previous step).
__global__ void k_mel() {
  const int wg = blockIdx.x, tid = threadIdx.x;
  if (wg < 16) {
    const int e = wg * 256 + tid;
    float s = 0.f;
    for (int w = 0; w < 64; ++w) s += g_pmel[w * 4096 + e];
    g_melsum[e] = s;
  } else if (tid < 32) {
    float s = 0.f;
    for (int w = 0; w < 64; ++w) s += g_pgate[w * 32 + tid];
    g_gatesum[tid] = s;
  }
}

// S1: GRU0 (WGs 0..63); WGs 64..95 write step t-1 outputs (fp32).
__global__ void k_s1(int t, const float* __restrict__ b_ih0,
                     const float* __restrict__ bp, const float* __restrict__ bg,
                     const int* __restrict__ lens,
                     float* __restrict__ out, int out_size) {
  const int wg = blockIdx.x, tid = threadIdx.x;
  const int lane = tid & 63, wv = tid >> 6;
  __shared__ __align__(16) float sh[1536];
  if (wg < 64) {
    if (t >= TM) return;
    const int qa = (wv < 2) ? wv * 2 : wv + 2;
    const int qb = (wv < 2) ? wv * 2 + 1 : -1;
    const ushort_t* SW_ih0 = g_sw + SB_IH0;
    float4v acc;
    { int g = qa >> 1, mu = qa & 1;
      acc = (t > 0) ? gemm_s1(g_melsum, bp, SW_ih0, g * 64 + wg, mu, lane)
                    : float4v{0.f, 0.f, 0.f, 0.f};
      put_tile(sh, qa, lane, acc); }
    if (qb >= 0) { int g = qb >> 1, mu = qb & 1;
      acc = (t > 0) ? gemm_s1(g_melsum, bp, SW_ih0, g * 64 + wg, mu, lane)
                    : float4v{0.f, 0.f, 0.f, 0.f};
      put_tile(sh, qb, lane, acc); }
    __syncthreads();
    const int jl = tid & 15, mr = tid >> 4, jg = wg * 16 + jl;
    const float bir = b_ih0[jg], biz = b_ih0[1024 + jg], bin = b_ih0[2048 + jg];
#pragma unroll
    for (int mu = 0; mu < 2; ++mu) {
      const int b = mu * 16 + mr;
      float gr = sh[mu * 256 + tid]       + bir + g_gh0[b * 3072 + jg];
      float gz = sh[(2 + mu) * 256 + tid] + biz + g_gh0[b * 3072 + 1024 + jg];
      float gn = sh[(4 + mu) * 256 + tid] + bin;
      float r = sigm(gr), z = sigm(gz);
      float nn = tanhf(gn + r * g_gh0[b * 3072 + 2048 + jg]);
      float h = (1.f - z) * nn + z * g_h0f[b * 1024 + jg];
      g_h0f[b * 1024 + jg] = h; g_h0b[b * 1024 + jg] = f2b(h);
    }
  } else {
    if (t == 0) return;
    const int fo = (wg - 64) * 256 + tid;
    if (fo < 4096) {
      const int b = fo >> 7, m = fo & 127;
      const bool mk = (t - 1) > lens[b];
      float v = mk ? 0.f : g_melsum[fo] + bp[m];
      int idx = b * 51200 + (t - 1) * 128 + m;
      if (idx < out_size) out[idx] = v;
    } else if (fo < 4128) {
      const int b = fo - 4096;
      const bool mk = (t - 1) > lens[b];
      float g = mk ? 1000.f : g_gatesum[b] + bg[0];
      int idx = 1638400 + b * 400 + (t - 1);
      if (idx < out_size) out[idx] = g;
    }
  }
}

// S2: GRU1 (64 WGs).
__global__ void k_s2(const float* __restrict__ b_ih1) {
  const int wg = blockIdx.x, tid = threadIdx.x;
  const int lane = tid & 63, wv = tid >> 6;
  __shared__ __align__(16) float sh[1536];
  const int qa = (wv < 2) ? wv * 2 : wv + 2;
  const int qb = (wv < 2) ? wv * 2 + 1 : -1;
  const ushort_t* SW_ih1 = g_sw + SB_IH1;
  { int g = qa >> 1, mu = qa & 1;
    put_tile(sh, qa, lane, gemm_bf16(g_h0b, 1024, SW_ih1, g * 64 + wg, mu, lane)); }
  if (qb >= 0) { int g = qb >> 1, mu = qb & 1;
    put_tile(sh, qb, lane, gemm_bf16(g_h0b, 1024, SW_ih1, g * 64 + wg, mu, lane)); }
  __syncthreads();
  const int jl = tid & 15, mr = tid >> 4, jg = wg * 16 + jl;
  const float bir = b_ih1[jg], biz = b_ih1[1024 + jg], bin = b_ih1[2048 + jg];
#pragma unroll
  for (int mu = 0; mu < 2; ++mu) {
    const int b = mu * 16 + mr;
    float gr = sh[mu * 256 + tid]       + bir + g_gh1[b * 3072 + jg];
    float gz = sh[(2 + mu) * 256 + tid] + biz + g_gh1[b * 3072 + 1024 + jg];
    float gn = sh[(4 + mu) * 256 + tid] + bin;
    float r = sigm(gr), z = sigm(gz);
    float nn = tanhf(gn + r * g_gh1[b * 3072 + 2048 + jg]);
    float h = (1.f - z) * nn + z * g_h1f[b * 1024 + jg];
    g_h1f[b * 1024 + jg] = h; g_h1b[b * 1024 + jg] = f2b(h);
  }
}

// S2b: gh0' (WGs 0..63), gh1' (64..127), u~ (128..191), c_buf (192).
__global__ void k_s2b(const float* __restrict__ b_hh0,
                      const float* __restrict__ b_hh1,
                      const float* __restrict__ b_attn) {
  const int wg = blockIdx.x, tid = threadIdx.x;
  const int lane = tid & 63, wv = tid >> 6;
  __shared__ __align__(16) float sh[1536];
  const int qa = (wv < 2) ? wv * 2 : wv + 2;
  const int qb = (wv < 2) ? wv * 2 + 1 : -1;
  if (wg < 128) {
    const ushort_t* Ab = (wg < 64) ? g_h0b : g_h1b;
    const ushort_t* Bw = g_sw + ((wg < 64) ? SB_HH0 : SB_HH1);
    const float* bhh = (wg < 64) ? b_hh0 : b_hh1;
    float* ghb = (wg < 64) ? g_gh0 : g_gh1;
    const int w16 = wg & 63;
    { int g = qa >> 1, mu = qa & 1;
      put_tile(sh, qa, lane, gemm_bf16(Ab, 1024, Bw, g * 64 + w16, mu, lane)); }
    if (qb >= 0) { int g = qb >> 1, mu = qb & 1;
      put_tile(sh, qb, lane, gemm_bf16(Ab, 1024, Bw, g * 64 + w16, mu, lane)); }
    __syncthreads();
    const int jl = tid & 15, mr = tid >> 4, jg = w16 * 16 + jl;
#pragma unroll
    for (int mu = 0; mu < 2; ++mu) {
      const int b = mu * 16 + mr;
#pragma unroll
      for (int g = 0; g < 3; ++g)
        ghb[b * 3072 + g * 1024 + jg] = sh[(g * 2 + mu) * 256 + tid] + bhh[g * 1024 + jg];
    }
  } else if (wg < 192) {
    const int nt = wg - 128;
    if (wv < 2) put_tile(sh, wv, lane, gemm_bf16(g_h1b, 1024, g_sw + SB_AT, nt, wv, lane));
    __syncthreads();
    const int nl = tid & 15, mr = tid >> 4, n = nt * 16 + nl;
    g_ubuf[mr * 1024 + n]        = sh[tid];
    g_ubuf[(16 + mr) * 1024 + n] = sh[256 + tid];
  } else {
    const int b = tid >> 3, seg = tid & 7;
    const float* hp = g_h1f + b * 1024 + seg * 128;
    const float* ba = b_attn + seg * 128;
    float s = 0.f;
    for (int k = 0; k < 128; ++k) s += hp[k] * ba[k];
    for (int off = 1; off < 8; off <<= 1) s += __shfl_xor(s, off, 64);
    if (seg == 0) g_cbuf[b] = s;
  }
}

// S3: attention partials. WG (b, slot): 64 enc timesteps, write slot partials.
__global__ void k_s3(const float* __restrict__ enc) {
  const int wg = blockIdx.x, tid = threadIdx.x;
  const int lane = tid & 63, wv = tid >> 6;
  __shared__ __align__(16) float sh[4160];
  const int b = wg >> 3, slot = wg & 7;
  const float* ub = g_ubuf + b * 1024;
  float4v u[4];
#pragma unroll
  for (int c = 0; c < 4; ++c) u[c] = *(const float4v*)(ub + c * 256 + lane * 4);
  const float cb = g_cbuf[b];
  float4v cx[4] = {{0.f,0.f,0.f,0.f},{0.f,0.f,0.f,0.f},{0.f,0.f,0.f,0.f},{0.f,0.f,0.f,0.f}};
  float sw = 0.f;
  const int t0 = slot * 64 + wv * 16;
  for (int it = 0; it < 16; ++it) {
    const float* encp = enc + ((size_t)(b * 512 + t0 + it) * 1024) + lane * 4;
    float4v e[4];
#pragma unroll
    for (int c = 0; c < 4; ++c) e[c] = *(const float4v*)(encp + c * 256);
    float s = 0.f;
#pragma unroll
    for (int c = 0; c < 4; ++c)
#pragma unroll
      for (int j = 0; j < 4; ++j) s += u[c][j] * e[c][j];
    for (int off = 1; off < 64; off <<= 1) s += __shfl_xor(s, off, 64);
    float sc = fminf(fmaxf(s + cb, -70.f), 70.f);   // identity in legit regime
    const float p = __expf(sc);
    sw += p;
#pragma unroll
    for (int c = 0; c < 4; ++c) cx[c] += p * e[c];
  }
#pragma unroll
  for (int c = 0; c < 4; ++c)
    *(float4v*)&sh[wv * 1024 + c * 256 + lane * 4] = cx[c];
  if (lane == 0) sh[4096 + wv] = sw;
  __syncthreads();
  float4v t4 = {0.f, 0.f, 0.f, 0.f};
#pragma unroll
  for (int v = 0; v < 4; ++v) t4 += *(const float4v*)&sh[v * 1024 + tid * 4];
  *(float4v*)&g_pctx[(size_t)(slot * 32 + b) * 1024 + tid * 4] = t4;
  if (tid == 0)
    g_pden[slot * 32 + b] = sh[4096] + sh[4097] + sh[4098] + sh[4099];
}

// Reduce ctx partials: 32 WGs (one per batch).
__global__ void k_red() {
  const int b = blockIdx.x, tid = threadIdx.x;
  float4v t4 = {0.f, 0.f, 0.f, 0.f};
#pragma unroll
  for (int s = 0; s < 8; ++s)
    t4 += *(const float4v*)&g_pctx[(size_t)(s * 32 + b) * 1024 + tid * 4];
  *(float4v*)&g_ctxn[b * 1024 + tid * 4] = t4;
  if (tid == 0) {
    float d = 0.f;
#pragma unroll
    for (int s = 0; s < 8; ++s) d += g_pden[s * 32 + b];
    g_sden[b] = d;
  }
}

// S4: co = tanh([h1|ctx]@Wc^T + bc); mel/gate partials per WG (64 WGs).
__global__ void k_s4(const float* __restrict__ bc, const float* __restrict__ Wp,
                     const float* __restrict__ Wg) {
  const int wg = blockIdx.x, tid = threadIdx.x;
  const int lane = tid & 63, wv = tid >> 6;
  __shared__ __align__(16) float sh[2048];
  if (wv < 2)
    put_tile(sh, wv, lane, gemm_s4(g_h1b, g_ctxn, g_sden, g_sw + SB_WC, wg, wv, lane));
  __syncthreads();
  const int jl = tid & 15, mr = tid >> 4;
  const float bcv = bc[wg * 16 + jl];
#pragma unroll
  for (int mu = 0; mu < 2; ++mu) {
    const int b = mu * 16 + mr;
    sh[1536 + b * 16 + jl] = tanhf(sh[mu * 256 + tid] + bcv);
  }
  __syncthreads();
  const int b2 = tid >> 3, mg = tid & 7;
  const float* cop = &sh[1536 + b2 * 16];
  for (int mm = 0; mm < 16; ++mm) {
    const int m = mg * 16 + mm;
    const float* wp = Wp + m * 1024 + wg * 16;
    float s = 0.f;
#pragma unroll
    for (int j2 = 0; j2 < 16; ++j2) s += wp[j2] * cop[j2];
    g_pmel[wg * 4096 + b2 * 128 + m] = s;
  }
  if (tid < 32) {
    const float* cop2 = &sh[1536 + tid * 16];
    const float* wgp = Wg + wg * 16;
    float g = 0.f;
#pragma unroll
    for (int j2 = 0; j2 < 16; ++j2) g += wgp[j2] * cop2[j2];
    g_pgate[wg * 32 + tid] = g;
  }
}

extern "C" void kernel_launch(void* const* d_in, const int* in_sizes, int n_in,
                              void* d_out, int out_size, void* d_ws, size_t ws_size,
                              hipStream_t stream) {
  const float* ehid  = (const float*)d_in[0];
  const float* enc   = (const float*)d_in[1];
  const int*   lens  = (const int*)d_in[3];
  const float* W_attn= (const float*)d_in[4];
  const float* b_attn= (const float*)d_in[5];
  const float* W_ih0 = (const float*)d_in[6];
  const float* W_hh0 = (const float*)d_in[7];
  const float* b_ih0 = (const float*)d_in[8];
  const float* b_hh0 = (const float*)d_in[9];
  const float* W_ih1 = (const float*)d_in[10];
  const float* W_hh1 = (const float*)d_in[11];
  const float* b_ih1 = (const float*)d_in[12];
  const float* b_hh1 = (const float*)d_in[13];
  const float* Wc    = (const float*)d_in[14];
  const float* bc    = (const float*)d_in[15];
  const float* Wp    = (const float*)d_in[16];
  const float* bp    = (const float*)d_in[17];
  const float* Wg    = (const float*)d_in[18];
  const float* bg    = (const float*)d_in[19];
  float* out = (float*)d_out;

  k_swz<<<6336, 256, 0, stream>>>(W_ih0, W_ih1, W_hh0, W_hh1, W_attn, Wc);
  k_init<<<306, 256, 0, stream>>>(ehid, lens, out, out_size);
  k_s2b<<<193, 256, 0, stream>>>(b_hh0, b_hh1, b_attn);   // gh for step 0
  for (int t = 0; t < TM; ++t) {
    k_mel<<<17, 256, 0, stream>>>();
    k_s1<<<96, 256, 0, stream>>>(t, b_ih0, bp, bg, lens, out, out_size);
    k_s2<<<64, 256, 0, stream>>>(b_ih1);
    k_s2b<<<193, 256, 0, stream>>>(b_hh0, b_hh1, b_attn);
    k_s3<<<256, 256, 0, stream>>>(enc);
    k_red<<<32, 256, 0, stream>>>();
    k_s4<<<64, 256, 0, stream>>>(bc, Wp, Wg);
  }
  k_mel<<<17, 256, 0, stream>>>();
  k_s1<<<96, 256, 0, stream>>>(TM, b_ih0, bp, bg, lens, out, out_size);
}